// Round 17
// baseline (396.697 us; speedup 1.0000x reference)
//
#include <hip/hip_runtime.h>
#include <hip/hip_bf16.h>

// B=64 (LSTM time axis via torch batch_first quirk), L=64 (only col 63 used),
// N=256, C=8, Ct=4 -> NQ=1024 sequences, H=128, 4H=512, RH1=128, RH2=64, S=4.
//
// fp16 scheme (R14, passing at 1.95e-3): fp16 operands, fp32 accum.
// R17: LSTM re-tiled for TLP - 512 blocks x 256 thr (4 waves), 2 seqs/block,
// 2 INDEPENDENT blocks per CU (separate barrier groups): one block's serial
// step chain hides under the other's. Each wave covers 32 gate-cols
// (8 C-tiles x 5 planes = 40 MFMA/step); lane (lk<2) owns 2 items (cc[2]).
// R11-R16 falsified residency/conflicts/LDS-volume/load-latency/chain-depth/
// issue-count as binding for the old 1-block/CU lockstep structure.

typedef __attribute__((ext_vector_type(8))) _Float16 half8;  // 8 f16, 4 VGPRs
typedef __attribute__((ext_vector_type(4))) float f32x4;

#define MFMAH(a, b, c) __builtin_amdgcn_mfma_f32_16x16x32_f16(a, b, c, 0, 0, 0)

__device__ __forceinline__ float sigf(float x)   { return 1.0f / (1.0f + __expf(-x)); }
__device__ __forceinline__ float tanh_f(float x) { return 1.0f - 2.0f / (__expf(2.0f * x) + 1.0f); }

// ---------------- one merged prep kernel, vectorized x8 ----------------
__global__ void prep_k(const float* __restrict__ x, const float* __restrict__ hi,
                       const float* __restrict__ W1, const float* __restrict__ W2,
                       const float* __restrict__ W3, const float* __restrict__ W_hh,
                       const float* __restrict__ W_ih,
                       _Float16* __restrict__ cur16, _Float16* __restrict__ hi16,
                       _Float16* __restrict__ wp1, _Float16* __restrict__ wp2,
                       _Float16* __restrict__ wp3, _Float16* __restrict__ wpB)
{
    int i = blockIdx.x * 256 + threadIdx.x;
    if (i < 65536) {                                    // cur16 <- x[:,63,:,:], x8
        int e = i * 8;
        int b = e >> 13, rem = e & 8191;
        const float* src = x + (size_t)b * 524288 + 63 * 8192 + rem;
        half8 v;
#pragma unroll
        for (int k = 0; k < 8; ++k) v[k] = (_Float16)src[k];
        *(half8*)(cur16 + e) = v;
        return;
    }
    i -= 65536;
    if (i < 262144) {                                   // hi16, x8
        int e = i * 8;
        half8 v;
#pragma unroll
        for (int k = 0; k < 8; ++k) v[k] = (_Float16)hi[e + k];
        *(half8*)(hi16 + e) = v;
        return;
    }
    i -= 262144;
    if (i < 32768) {                       // wp1 [kt8][nt8][512]; K=256 = [hs|hi]
        int fragid = i >> 9, lj = i & 511;
        int kt = fragid >> 3, nt = fragid & 7;
        int l = lj >> 3, j = lj & 7;
        int k = kt * 32 + (l >> 4) * 8 + j;
        int o = nt * 16 + (l & 15);
        wp1[i] = (_Float16)W1[o * 257 + k];
        return;
    }
    i -= 32768;
    if (i < 8192) {                        // wp2 [kt4][nt4][512]; K=128
        int fragid = i >> 9, lj = i & 511;
        int kt = fragid >> 2, nt = fragid & 3;
        int l = lj >> 3, j = lj & 7;
        int k = kt * 32 + (l >> 4) * 8 + j;
        int o = nt * 16 + (l & 15);
        wp2[i] = (_Float16)W2[o * 128 + k];
        return;
    }
    i -= 8192;
    if (i < 1024) {                        // wp3 [kt2][512]; K=64
        int kt = i >> 9, lj = i & 511;
        int l = lj >> 3, j = lj & 7;
        int k = kt * 32 + (l >> 4) * 8 + j;
        int c = l & 15;
        wp3[i] = (_Float16)((c < 8) ? W3[c * 64 + k] : 0.0f);
        return;
    }
    i -= 1024;
    if (i < 81920) {                       // wpB [kt5][ntile32][512]
        int frag = i >> 9, lj = i & 511;
        int kt = frag >> 5, ntile = frag & 31;
        int l = lj >> 3, j = lj & 7;
        int klocal = (l >> 4) * 8 + j;
        int col = ntile * 16 + (l & 15);
        float v;
        if (kt < 4) v = W_hh[col * 128 + kt * 32 + klocal];
        else        v = (klocal < 8) ? W_ih[col * 8 + klocal] : 0.0f;
        wpB[i] = (_Float16)v;
    }
}

// ---------------- LSTM scan: fp16 MFMA, 512 blocks x 4 waves ----------------
// Block owns 2 seqs (q0 = blockIdx*2) at C-rows {0,4}; 2 blocks/CU, separate
// barrier groups -> independent recurrences overlap on the SIMDs.
// Wave cg covers gate cols [cg*32, cg*32+32) = ntiles {2cg, 2cg+1} for all 4
// gates (order f,i,g,o): 8 C-tiles x (1 x-plane + 4 h-planes) = 40 MFMA/step.
// A-row broadcast: row r is fed h[seq (r>>2)&1]; C rows 0/4 are the real ones.
// Lane (lk<2, li) owns items (seq=lk, cols (2cg+nt)*16+li), nt=0,1; cc[2].
// Weight frags pinned in AGPRs; bias added at scalar extraction; x slice in
// LDS; hs register-direct; in-loop barrier drains lgkmcnt only.
__global__ __launch_bounds__(256, 2) void lstm_mfma_k(
    const _Float16* __restrict__ cur16, const _Float16* __restrict__ wpB,
    const float* __restrict__ b_ih, const float* __restrict__ b_hh,
    _Float16* __restrict__ hs16)
{
    __shared__ __align__(16) _Float16 zone[2][4][2][40];  // [buf][ktpl][seq][32+8]
    __shared__ __align__(16) _Float16 xz[64][16];         // [step][2 seqs x 8]

    const int t  = threadIdx.x;
    const int cg = t >> 6, l = t & 63;
    const int li = l & 15, lk = l >> 4;
    const int q0 = blockIdx.x * 2;

    // B-frags: gate order {f,i,g,o} = src {1,0,2,3}; [g][nt][kt0-3 h, kt4 x]
    const int gsrc[4] = {1, 0, 2, 3};
    half8 bw[4][2][5];
#pragma unroll
    for (int g = 0; g < 4; ++g)
#pragma unroll
        for (int nt = 0; nt < 2; ++nt)
#pragma unroll
            for (int kt = 0; kt < 5; ++kt) {
                bw[g][nt][kt] = *(const half8*)(wpB +
                    (size_t)(kt * 32 + gsrc[g] * 8 + 2 * cg + nt) * 512 + l * 8);
                asm volatile("" : "+a"(bw[g][nt][kt]));   // pin to AGPR
            }

    float bias[4][2];
#pragma unroll
    for (int g = 0; g < 4; ++g)
#pragma unroll
        for (int nt = 0; nt < 2; ++nt) {
            int gc = gsrc[g] * 128 + (2 * cg + nt) * 16 + li;
            bias[g][nt] = b_ih[gc] + b_hh[gc];
        }

    if (t < 320) ((uint*)zone)[t] = 0;        // 640 halfs = 320 dwords
    if (t < 128) {                            // stage x slice: 64 x 2 x 8 = 2 KB
        int step = t >> 1, s = t & 1;
        *(uint4*)&xz[step][s * 8] =
            *(const uint4*)(cur16 + (size_t)step * 8192 + (q0 + s) * 8);
    }
    float cc0 = 0.0f, cc1 = 0.0f;
    __syncthreads();

    const int sli  = (li >> 2) & 1;           // A-row -> seq broadcast map
    const int roff = sli * 40 + lk * 8;       // read offset within a kt plane
    const _Float16* xrd = &xz[0][sli * 8];

    // hs store base: lane (cg, lk<2, li); item cols cg*32 + nt*16 + li
    _Float16* ph = hs16 + (size_t)(q0 + lk) * 128 + cg * 32 + li;

    const f32x4 z4 = (f32x4){0.0f, 0.0f, 0.0f, 0.0f};

    auto dostep = [&](int step, int p) {
        const int pn = p ^ 1;
        half8 xa = *(const half8*)(xrd + step * 16);
        half8 ah[4];
#pragma unroll
        for (int kt = 0; kt < 4; ++kt)
            ah[kt] = *(const half8*)&zone[p][kt][0][roff];

        __builtin_amdgcn_s_setprio(1);
        float pv[4][2];
#pragma unroll
        for (int g = 0; g < 4; ++g) {
            f32x4 a0 = MFMAH(xa, bw[g][0][4], z4);
            f32x4 a1 = MFMAH(xa, bw[g][1][4], z4);
#pragma unroll
            for (int kt = 0; kt < 4; ++kt) {
                a0 = MFMAH(ah[kt], bw[g][0][kt], a0);
                a1 = MFMAH(ah[kt], bw[g][1][kt], a1);
            }
            pv[g][0] = a0[0] + bias[g][0];
            pv[g][1] = a1[0] + bias[g][1];
        }

        // gates {f,i,g,o}; two items per lane (nt 0,1)
        cc0 = sigf(pv[0][0]) * cc0 + sigf(pv[1][0]) * tanh_f(pv[2][0]);
        float hv0 = sigf(pv[3][0]) * tanh_f(cc0);
        cc1 = sigf(pv[0][1]) * cc1 + sigf(pv[1][1]) * tanh_f(pv[2][1]);
        float hv1 = sigf(pv[3][1]) * tanh_f(cc1);
        __builtin_amdgcn_s_setprio(0);
        _Float16 h0 = (_Float16)hv0, h1 = (_Float16)hv1;
        if (lk < 2) {
            zone[pn][cg][lk][li]      = h0;   // col = cg*32 + li      (nt=0)
            zone[pn][cg][lk][16 + li] = h1;   // col = cg*32 + 16 + li (nt=1)
            ph[(size_t)step * 131072]      = h0;   // fire-and-forget
            ph[(size_t)step * 131072 + 16] = h1;
        }
        asm volatile("s_waitcnt lgkmcnt(0)\n\ts_barrier" ::: "memory");
    };

    for (int s2 = 0; s2 < 32; ++s2) {
        dostep(s2 * 2,     0);
        dostep(s2 * 2 + 1, 1);
    }
}

// ---------------- MLP + head for one roll: fp16 MFMA ----------
// 1024 wgs (b x 16 q-groups) x 256 thr (4 waves). wg owns 64 items (M=64).
// GEMM1 A-frags double-buffered: load kt+1 while computing kt.
__global__ __launch_bounds__(256, 3) void mlp_mfma_k(
    const _Float16* __restrict__ hs16, const _Float16* __restrict__ hi16,
    const float* __restrict__ r, int jstep,
    const _Float16* __restrict__ wp1, const _Float16* __restrict__ wp2,
    const _Float16* __restrict__ wp3,
    const float* __restrict__ W1, const float* __restrict__ b1,
    const float* __restrict__ b2, const float* __restrict__ b3,
    const float* __restrict__ Wf, const float* __restrict__ bfp,
    _Float16* __restrict__ cur16, float* __restrict__ out)
{
    __shared__ __align__(16) _Float16 h1f[4 * 4 * 640];   // 20KB
    __shared__ __align__(16) _Float16 h2f[2 * 4 * 640];   // 10KB

    const int t = threadIdx.x;
    const int w = t >> 6, l = t & 63;
    const int lrow = l & 15, lk = l >> 4;
    const int b = blockIdx.x >> 4;
    const int qb = (blockIdx.x & 15) * 64;
    const float rb = r[b * 4 + jstep];

    // ============ GEMM1: h1 = relu([hs|hi|r] @ W1^T + b1), K=256 ============
    f32x4 acc[4][2];
#pragma unroll
    for (int nt = 0; nt < 2; ++nt) {
        int col = w * 32 + nt * 16 + lrow;
        float bias = b1[col] + rb * W1[col * 257 + 256];
#pragma unroll
        for (int mt = 0; mt < 4; ++mt)
            acc[mt][nt] = (f32x4){bias, bias, bias, bias};
    }

    auto loadA = [&](int kt, half8* av) {
#pragma unroll
        for (int mt = 0; mt < 4; ++mt) {
            int q = qb + mt * 16 + lrow;
            if (kt < 4)
                av[mt] = *(const half8*)(hs16 + (size_t)(b * 1024 + q) * 128
                                          + kt * 32 + lk * 8);
            else
                av[mt] = *(const half8*)(hi16 + (size_t)(b * 256 + (q >> 2)) * 128
                                          + (kt - 4) * 32 + lk * 8);
        }
    };

    half8 avA[4], avB[4];
    loadA(0, avA);
#pragma unroll
    for (int kt = 0; kt < 8; ++kt) {
        half8* cur = (kt & 1) ? avB : avA;
        half8* nxt = (kt & 1) ? avA : avB;
        if (kt < 7) loadA(kt + 1, nxt);       // prefetch next kt's A-frags
#pragma unroll
        for (int nt = 0; nt < 2; ++nt) {
            half8 bv = *(const half8*)(wp1 + (size_t)(kt * 8 + w * 2 + nt) * 512 + l * 8);
#pragma unroll
            for (int mt = 0; mt < 4; ++mt)
                acc[mt][nt] = MFMAH(cur[mt], bv, acc[mt][nt]);
        }
    }

    // epilogue1: relu -> fp16 -> h1 plane w
#pragma unroll
    for (int mt = 0; mt < 4; ++mt)
#pragma unroll
        for (int nt = 0; nt < 2; ++nt)
#pragma unroll
            for (int reg = 0; reg < 4; ++reg) {
                float v = fmaxf(acc[mt][nt][reg], 0.0f);
                int s = lk * 4 + reg, jj = nt * 16 + lrow;
                h1f[(w * 4 + mt) * 640 + s * 40 + jj] = (_Float16)v;
            }
    __syncthreads();

    // ============ GEMM2: h2 = relu(h1 @ W2^T + b2), K=128, cols 16w.. =======
    f32x4 acc2[4];
    {
        float bias = b2[16 * w + lrow];
#pragma unroll
        for (int mt = 0; mt < 4; ++mt)
            acc2[mt] = (f32x4){bias, bias, bias, bias};
    }
#pragma unroll
    for (int kt = 0; kt < 4; ++kt) {
        half8 bv = *(const half8*)(wp2 + (size_t)(kt * 4 + w) * 512 + l * 8);
#pragma unroll
        for (int mt = 0; mt < 4; ++mt) {
            half8 a = *(const half8*)&h1f[(kt * 4 + mt) * 640 + lrow * 40 + lk * 8];
            acc2[mt] = MFMAH(a, bv, acc2[mt]);
        }
    }
#pragma unroll
    for (int mt = 0; mt < 4; ++mt)
#pragma unroll
        for (int reg = 0; reg < 4; ++reg) {
            float v = fmaxf(acc2[mt][reg], 0.0f);
            int s = lk * 4 + reg, jl2 = (w & 1) * 16 + lrow;
            h2f[((w >> 1) * 4 + mt) * 640 + s * 40 + jl2] = (_Float16)v;
        }
    __syncthreads();

    // ============ GEMM3: pr = h2 @ W3^T + b3, K=64; wave w -> rows 16w.. ===
    f32x4 acc3 = (f32x4){0.0f, 0.0f, 0.0f, 0.0f};
#pragma unroll
    for (int kt = 0; kt < 2; ++kt) {
        half8 a  = *(const half8*)&h2f[(kt * 4 + w) * 640 + lrow * 40 + lk * 8];
        half8 bv = *(const half8*)(wp3 + (size_t)kt * 512 + l * 8);
        acc3 = MFMAH(a, bv, acc3);
    }

    // epilogue3: cur16 <- fp16(pr); head: sum relu(pr)*Wf over C, then Ct
    const int c = lrow;
    const float b3v = (c < 8) ? b3[c] : 0.0f;
    const float wfv = (c < 8) ? Wf[c] : 0.0f;
    float fr[4];
#pragma unroll
    for (int reg = 0; reg < 4; ++reg) {
        float pr = acc3[reg] + b3v;
        if (c < 8) {
            int row = 16 * w + lk * 4 + reg;
            cur16[((size_t)(b * 1024 + qb + row)) * 8 + c] = (_Float16)pr;
        }
        fr[reg] = (c < 8) ? fmaxf(pr, 0.0f) * wfv : 0.0f;
    }
#pragma unroll
    for (int reg = 0; reg < 4; ++reg) {
        fr[reg] += __shfl_xor(fr[reg], 1);
        fr[reg] += __shfl_xor(fr[reg], 2);
        fr[reg] += __shfl_xor(fr[reg], 4);
    }
    if ((l & 15) == 0) {
        int n = (qb + 16 * w + lk * 4) >> 2;
        float v = fr[0] + fr[1] + fr[2] + fr[3] + 4.0f * bfp[0];
        out[(size_t)(b * 256 + n) * 4 + jstep] = v;
    }
}

extern "C" void kernel_launch(void* const* d_in, const int* in_sizes, int n_in,
                              void* d_out, int out_size, void* d_ws, size_t ws_size,
                              hipStream_t stream)
{
    const float* x   = (const float*)d_in[0];
    const float* hi  = (const float*)d_in[1];
    const float* r   = (const float*)d_in[2];
    const float* Wih = (const float*)d_in[3];
    const float* Whh = (const float*)d_in[4];
    const float* bih = (const float*)d_in[5];
    const float* bhh = (const float*)d_in[6];
    const float* W1  = (const float*)d_in[7];
    const float* b1  = (const float*)d_in[8];
    const float* W2  = (const float*)d_in[9];
    const float* b2  = (const float*)d_in[10];
    const float* W3  = (const float*)d_in[11];
    const float* b3  = (const float*)d_in[12];
    const float* Wf  = (const float*)d_in[13];
    const float* bf  = (const float*)d_in[14];
    float* out = (float*)d_out;

    _Float16* cur16 = (_Float16*)d_ws;                 // 524288
    _Float16* hs16  = cur16 + 524288;                  // 8388608 (16 MB)
    _Float16* hi16  = hs16 + 8388608;                  // 2097152
    _Float16* wp1   = hi16 + 2097152;                  // 32768
    _Float16* wp2   = wp1 + 32768;                     // 8192
    _Float16* wp3   = wp2 + 8192;                      // 1024
    _Float16* wpB   = wp3 + 1024;                      // 81920

    prep_k<<<1764, 256, 0, stream>>>(x, hi, W1, W2, W3, Whh, Wih,
                                     cur16, hi16, wp1, wp2, wp3, wpB);
    for (int j = 0; j < 4; ++j) {
        lstm_mfma_k<<<512, 256, 0, stream>>>(cur16, wpB, bih, bhh, hs16);
        mlp_mfma_k<<<1024, 256, 0, stream>>>(hs16, hi16, r, j, wp1, wp2, wp3,
                                             W1, b1, b2, b3, Wf, bf, cur16, out);
    }
}

// Round 18
// 281.292 us; speedup vs baseline: 1.4103x; 1.4103x over previous
//
#include <hip/hip_runtime.h>
#include <hip/hip_bf16.h>

// B=64 (LSTM time axis via torch batch_first quirk), L=64 (only col 63 used),
// N=256, C=8, Ct=4 -> NQ=1024 sequences, H=128, 4H=512, RH1=128, RH2=64, S=4.
//
// R18 MEGAKERNEL: block b owns seqs q0=4b..4b+3 (= Ct-group of n=b). Its LSTM
// needs only cur[*][q0..3], which only its own MLP items produce -> blocks are
// fully independent across all 4 rolls. One kernel does (lstm64 -> mlp256)x4
// per block with hs/cur entirely in LDS (no HBM round-trip, no launches).
// fp16 operands, fp32 accum (R14 scheme, passing at 1.95e-3). LSTM phase =
// R16 structure verbatim (best measured). MLP phase: 8 waves, 2 passes of 8
// M-tiles; r folded as 9th K-tile of GEMM1 (b varies per row in fused form).

typedef __attribute__((ext_vector_type(8))) _Float16 half8;  // 8 f16, 4 VGPRs
typedef __attribute__((ext_vector_type(4))) float f32x4;

#define MFMAH(a, b, c) __builtin_amdgcn_mfma_f32_16x16x32_f16(a, b, c, 0, 0, 0)

__device__ __forceinline__ float sigf(float x)   { return 1.0f / (1.0f + __expf(-x)); }
__device__ __forceinline__ float tanh_f(float x) { return 1.0f - 2.0f / (__expf(2.0f * x) + 1.0f); }

// ---------------- one merged prep kernel ----------------
// vec jobs (x8): hi16 262144. scalar: wp1 36864 (9 kt!) | wp2 8192 | wp3 1024
// | wpB 81920. total = 390144 = 1524 * 256.
__global__ void prep_k(const float* __restrict__ hi,
                       const float* __restrict__ W1, const float* __restrict__ W2,
                       const float* __restrict__ W3, const float* __restrict__ W_hh,
                       const float* __restrict__ W_ih,
                       _Float16* __restrict__ hi16, _Float16* __restrict__ wp1,
                       _Float16* __restrict__ wp2, _Float16* __restrict__ wp3,
                       _Float16* __restrict__ wpB)
{
    int i = blockIdx.x * 256 + threadIdx.x;
    if (i < 262144) {                                   // hi16, x8
        int e = i * 8;
        half8 v;
#pragma unroll
        for (int k = 0; k < 8; ++k) v[k] = (_Float16)hi[e + k];
        *(half8*)(hi16 + e) = v;
        return;
    }
    i -= 262144;
    if (i < 36864) {        // wp1 [kt9][nt8][512]; kt0-7: K=256=[hs|hi]; kt8: r col
        int fragid = i >> 9, lj = i & 511;
        int kt = fragid >> 3, nt = fragid & 7;
        int l = lj >> 3, j = lj & 7;
        int klocal = (l >> 4) * 8 + j;
        int o = nt * 16 + (l & 15);
        float v;
        if (kt < 8)      v = W1[o * 257 + kt * 32 + klocal];
        else             v = (klocal == 0) ? W1[o * 257 + 256] : 0.0f;
        wp1[i] = (_Float16)v;
        return;
    }
    i -= 36864;
    if (i < 8192) {                        // wp2 [kt4][nt4][512]; K=128
        int fragid = i >> 9, lj = i & 511;
        int kt = fragid >> 2, nt = fragid & 3;
        int l = lj >> 3, j = lj & 7;
        int k = kt * 32 + (l >> 4) * 8 + j;
        int o = nt * 16 + (l & 15);
        wp2[i] = (_Float16)W2[o * 128 + k];
        return;
    }
    i -= 8192;
    if (i < 1024) {                        // wp3 [kt2][512]; K=64
        int kt = i >> 9, lj = i & 511;
        int l = lj >> 3, j = lj & 7;
        int k = kt * 32 + (l >> 4) * 8 + j;
        int c = l & 15;
        wp3[i] = (_Float16)((c < 8) ? W3[c * 64 + k] : 0.0f);
        return;
    }
    i -= 1024;
    if (i < 81920) {                       // wpB [kt5][ntile32][512]
        int frag = i >> 9, lj = i & 511;
        int kt = frag >> 5, ntile = frag & 31;
        int l = lj >> 3, j = lj & 7;
        int klocal = (l >> 4) * 8 + j;
        int col = ntile * 16 + (l & 15);
        float v;
        if (kt < 4) v = W_hh[col * 128 + kt * 32 + klocal];
        else        v = (klocal < 8) ? W_ih[col * 8 + klocal] : 0.0f;
        wpB[i] = (_Float16)v;
    }
}

// ---------------- fused 4-roll megakernel: 256 blocks x 512 thr ------------
__global__ __launch_bounds__(512, 2) void fused_k(
    const float* __restrict__ x, const _Float16* __restrict__ hi16,
    const float* __restrict__ r, const _Float16* __restrict__ wpB,
    const float* __restrict__ b_ih, const float* __restrict__ b_hh,
    const _Float16* __restrict__ wp1, const _Float16* __restrict__ wp2,
    const _Float16* __restrict__ wp3, const float* __restrict__ b1,
    const float* __restrict__ b2, const float* __restrict__ b3,
    const float* __restrict__ Wf, const float* __restrict__ bfp,
    float* __restrict__ out)
{
    __shared__ __align__(16) _Float16 zone[2][4][640];   // 10 KB h planes
    __shared__ __align__(16) _Float16 xz[64][32];        // 4 KB x slice (=cur)
    __shared__ __align__(16) _Float16 hsL[256 * 130];    // 66.5 KB hs, pad 130
    __shared__ __align__(16) _Float16 h1L[128 * 132];    // 33.8 KB
    __shared__ __align__(16) _Float16 h2L[128 * 68];     // 17.4 KB

    const int t  = threadIdx.x;
    const int cg = t >> 6, l = t & 63;
    const int li = l & 15, lk = l >> 4;
    const int q0 = blockIdx.x * 4, nblk = blockIdx.x;

    // ---- LSTM weight frags (gate order f,i,g,o = src 1,0,2,3), AGPR-pinned
    const int gsrc[4] = {1, 0, 2, 3};
    half8 bw[4][5];
#pragma unroll
    for (int g = 0; g < 4; ++g)
#pragma unroll
        for (int kt = 0; kt < 5; ++kt) {
            bw[g][kt] = *(const half8*)(wpB + (size_t)(kt * 32 + gsrc[g] * 8 + cg) * 512 + l * 8);
            asm volatile("" : "+a"(bw[g][kt]));
        }
    f32x4 bs4[4];
#pragma unroll
    for (int g = 0; g < 4; ++g) {
        int gc = gsrc[g] * 128 + cg * 16 + li;
        float bv = b_ih[gc] + b_hh[gc];
        bs4[g] = (f32x4){bv, bv, bv, bv};
    }

    // ---- initial xz from x[:,63,q0..q0+3,:] (fp32 -> fp16)
    if (t < 256) {
        int step = t >> 2, tt = t & 3;
        const float* src = x + (size_t)step * 524288 + 63 * 8192 + (q0 + tt) * 8;
        half8 v;
#pragma unroll
        for (int k = 0; k < 8; ++k) v[k] = (_Float16)src[k];
        *(half8*)&xz[step][tt * 8] = v;
    }

    const int zpl  = cg >> 1;
    const int jl   = (cg & 1) * 16 + li;
    const int roff = (li & 12) * 40 + lk * 8;     // broadcast A-read offset
    const int srow = lk * 4;
    const _Float16* xrd = &xz[0][(li >> 2) * 8];
    const f32x4 z4 = (f32x4){0.0f, 0.0f, 0.0f, 0.0f};

    for (int j = 0; j < 4; ++j) {
        // ===================== LSTM phase (R16 structure) =====================
        for (int i = t; i < 1280; i += 512) ((uint*)zone)[i] = 0;   // buf 0 = 0
        float cc = 0.0f;
        __syncthreads();

        f32x4 accx[4];
        {
            half8 xa0 = *(const half8*)(xrd);
#pragma unroll
            for (int g = 0; g < 4; ++g)
                accx[g] = MFMAH(xa0, bw[g][4], bs4[g]);
        }

        auto dostep = [&](int step, int p) {
            const int pn = p ^ 1;
            half8 ah[4];
#pragma unroll
            for (int kt = 0; kt < 4; ++kt)
                ah[kt] = *(const half8*)&zone[p][kt][roff];

            __builtin_amdgcn_s_setprio(1);
            f32x4 a0[4], a1[4];
#pragma unroll
            for (int g = 0; g < 4; ++g) {
                a0[g] = MFMAH(ah[0], bw[g][0], accx[g]);
                a1[g] = MFMAH(ah[2], bw[g][2], z4);
            }
#pragma unroll
            for (int g = 0; g < 4; ++g) {
                a0[g] = MFMAH(ah[1], bw[g][1], a0[g]);
                a1[g] = MFMAH(ah[3], bw[g][3], a1[g]);
            }
            float pf = a0[0][0] + a1[0][0];
            float sf = sigf(pf);
            float pi = a0[1][0] + a1[1][0];
            float pg = a0[2][0] + a1[2][0];
            float po = a0[3][0] + a1[3][0];
            cc = sf * cc + sigf(pi) * tanh_f(pg);
            float hv = sigf(po) * tanh_f(cc);
            __builtin_amdgcn_s_setprio(0);
            _Float16 h16 = (_Float16)hv;
            zone[pn][zpl][srow * 40 + jl] = h16;
            hsL[(step * 4 + lk) * 130 + cg * 16 + li] = h16;   // LDS, not HBM
            asm volatile("s_waitcnt lgkmcnt(0)\n\ts_barrier" ::: "memory");

            // barrier shadow: next step's x-plane accumulation (step 63's
            // prefetch reads stale xz[0]; value unused - safe, pre-epilogue)
            half8 xn = *(const half8*)(xrd + ((step + 1) & 63) * 32);
#pragma unroll
            for (int g = 0; g < 4; ++g)
                accx[g] = MFMAH(xn, bw[g][4], bs4[g]);
        };
        for (int s2 = 0; s2 < 32; ++s2) {
            dostep(s2 * 2,     0);
            dostep(s2 * 2 + 1, 1);
        }

        // ===================== MLP phase: 2 passes x 8 M-tiles ================
        // item i = Mg*16 + row; b = i>>2 = Mg*4 + (row>>2); dq = i&3.
#pragma unroll 1
        for (int p = 0; p < 2; ++p) {
            // ---- GEMM1: wave cg owns N-tile cg (cols cg*16..+15), K = 9 kts
            f32x4 acc[8];
            {
                float bias = b1[cg * 16 + li];
#pragma unroll
                for (int m = 0; m < 8; ++m)
                    acc[m] = (f32x4){bias, bias, bias, bias};
            }
#pragma unroll
            for (int kt = 0; kt < 9; ++kt) {
                half8 bv = *(const half8*)(wp1 + (size_t)(kt * 8 + cg) * 512 + l * 8);
#pragma unroll
                for (int m = 0; m < 8; ++m) {
                    int Mg = p * 8 + m;
                    half8 av;
                    if (kt < 4) {
                        av = *(const half8*)&hsL[(Mg * 16 + li) * 130 + kt * 32 + lk * 8];
                    } else if (kt < 8) {
                        int b = Mg * 4 + (li >> 2);
                        av = *(const half8*)(hi16 + ((size_t)b * 256 + nblk) * 128
                                             + (kt - 4) * 32 + lk * 8);
                    } else {
                        int b = Mg * 4 + (li >> 2);
                        av = (half8){0, 0, 0, 0, 0, 0, 0, 0};
                        if (lk == 0) av[0] = (_Float16)r[b * 4 + j];
                    }
                    acc[m] = MFMAH(av, bv, acc[m]);
                }
            }
#pragma unroll
            for (int m = 0; m < 8; ++m)
#pragma unroll
                for (int reg = 0; reg < 4; ++reg) {
                    float v = fmaxf(acc[m][reg], 0.0f);
                    h1L[(m * 16 + lk * 4 + reg) * 132 + cg * 16 + li] = (_Float16)v;
                }
            __syncthreads();

            // ---- GEMM2: wave cg: N-tile n2 = cg&3, M-tiles (cg>>2)*4..+3
            {
                const int n2 = cg & 3, mg0 = (cg >> 2) * 4;
                f32x4 acc2[4];
                float bias = b2[n2 * 16 + li];
#pragma unroll
                for (int mi = 0; mi < 4; ++mi)
                    acc2[mi] = (f32x4){bias, bias, bias, bias};
#pragma unroll
                for (int kt = 0; kt < 4; ++kt) {
                    half8 bv = *(const half8*)(wp2 + (size_t)(kt * 4 + n2) * 512 + l * 8);
#pragma unroll
                    for (int mi = 0; mi < 4; ++mi) {
                        int m = mg0 + mi;
                        half8 av = *(const half8*)&h1L[(m * 16 + li) * 132 + kt * 32 + lk * 8];
                        acc2[mi] = MFMAH(av, bv, acc2[mi]);
                    }
                }
#pragma unroll
                for (int mi = 0; mi < 4; ++mi)
#pragma unroll
                    for (int reg = 0; reg < 4; ++reg) {
                        float v = fmaxf(acc2[mi][reg], 0.0f);
                        h2L[((mg0 + mi) * 16 + lk * 4 + reg) * 68 + n2 * 16 + li] = (_Float16)v;
                    }
            }
            __syncthreads();

            // ---- GEMM3 + epilogue: wave cg owns M-tile m = cg
            {
                f32x4 acc3 = z4;
#pragma unroll
                for (int kt = 0; kt < 2; ++kt) {
                    half8 av = *(const half8*)&h2L[(cg * 16 + li) * 68 + kt * 32 + lk * 8];
                    half8 bv = *(const half8*)(wp3 + (size_t)kt * 512 + l * 8);
                    acc3 = MFMAH(av, bv, acc3);
                }
                const int Mg = p * 8 + cg;
                const int c = li;
                const float b3v = (c < 8) ? b3[c] : 0.0f;
                const float wfv = (c < 8) ? Wf[c] : 0.0f;
                const int b = Mg * 4 + lk;
                float fr[4];
#pragma unroll
                for (int reg = 0; reg < 4; ++reg) {
                    float pr = acc3[reg] + b3v;
                    if (c < 8) xz[b][reg * 8 + c] = (_Float16)pr;   // next roll's x
                    fr[reg] = (c < 8) ? fmaxf(pr, 0.0f) * wfv : 0.0f;
                }
#pragma unroll
                for (int reg = 0; reg < 4; ++reg) {
                    fr[reg] += __shfl_xor(fr[reg], 1);
                    fr[reg] += __shfl_xor(fr[reg], 2);
                    fr[reg] += __shfl_xor(fr[reg], 4);
                }
                if (li == 0) {
                    float v = fr[0] + fr[1] + fr[2] + fr[3] + 4.0f * bfp[0];
                    out[((size_t)b * 256 + nblk) * 4 + j] = v;
                }
            }
            __syncthreads();
        }
    }
}

extern "C" void kernel_launch(void* const* d_in, const int* in_sizes, int n_in,
                              void* d_out, int out_size, void* d_ws, size_t ws_size,
                              hipStream_t stream)
{
    const float* x   = (const float*)d_in[0];
    const float* hi  = (const float*)d_in[1];
    const float* r   = (const float*)d_in[2];
    const float* Wih = (const float*)d_in[3];
    const float* Whh = (const float*)d_in[4];
    const float* bih = (const float*)d_in[5];
    const float* bhh = (const float*)d_in[6];
    const float* W1  = (const float*)d_in[7];
    const float* b1  = (const float*)d_in[8];
    const float* W2  = (const float*)d_in[9];
    const float* b2  = (const float*)d_in[10];
    const float* W3  = (const float*)d_in[11];
    const float* b3  = (const float*)d_in[12];
    const float* Wf  = (const float*)d_in[13];
    const float* bf  = (const float*)d_in[14];
    float* out = (float*)d_out;

    _Float16* hi16 = (_Float16*)d_ws;                  // 2097152
    _Float16* wp1  = hi16 + 2097152;                   // 36864 (9 kts)
    _Float16* wp2  = wp1 + 36864;                      // 8192
    _Float16* wp3  = wp2 + 8192;                       // 1024
    _Float16* wpB  = wp3 + 1024;                       // 81920

    prep_k<<<1524, 256, 0, stream>>>(hi, W1, W2, W3, Whh, Wih,
                                     hi16, wp1, wp2, wp3, wpB);
    fused_k<<<256, 512, 0, stream>>>(x, hi16, r, wpB, bih, bhh,
                                     wp1, wp2, wp3, b1, b2, b3, Wf, bf, out);
}

// Round 19
// 253.383 us; speedup vs baseline: 1.5656x; 1.1101x over previous
//
#include <hip/hip_runtime.h>
#include <hip/hip_bf16.h>

// B=64 (LSTM time axis via torch batch_first quirk), L=64 (only col 63 used),
// N=256, C=8, Ct=4 -> NQ=1024 sequences, H=128, 4H=512, RH1=128, RH2=64, S=4.
//
// R19 WAVEFRONT MEGAKERNEL: MLP item (b,q) of roll j needs LSTM_j only up to
// step b; LSTM_{j+1} step t needs MLP_j item b=t. So roll j runs at local
// step t_j = T - j: 67 global steps replace 256 serial LSTM steps + 8 MLP
// dispatches. The 16-row M-tile now holds 16 REAL recurrences (4 rolls x 4
// seqs; row r = (roll r>>2, seq r&3)) - same 20 MFMA/wave/step as before but
// zero padding waste. Per step the MLP is one 16-row M-tile (G1 9/wave,
// G2 4 on waves 0-3, G3+epilogue 2 on wave 0). hs never touches HBM.
// fp16 operands, fp32 accum (R14 scheme, passing 1.95e-3).

typedef __attribute__((ext_vector_type(8))) _Float16 half8;  // 8 f16, 4 VGPRs
typedef __attribute__((ext_vector_type(4))) float f32x4;

#define MFMAH(a, b, c) __builtin_amdgcn_mfma_f32_16x16x32_f16(a, b, c, 0, 0, 0)

__device__ __forceinline__ float sigf(float x)   { return 1.0f / (1.0f + __expf(-x)); }
__device__ __forceinline__ float tanh_f(float x) { return 1.0f - 2.0f / (__expf(2.0f * x) + 1.0f); }

// ---------------- one merged prep kernel (unchanged from R18) ----------------
// vec jobs (x8): hi16 262144. scalar: wp1 36864 (9 kt) | wp2 8192 | wp3 1024
// | wpB 81920. total = 390144 = 1524 * 256.
__global__ void prep_k(const float* __restrict__ hi,
                       const float* __restrict__ W1, const float* __restrict__ W2,
                       const float* __restrict__ W3, const float* __restrict__ W_hh,
                       const float* __restrict__ W_ih,
                       _Float16* __restrict__ hi16, _Float16* __restrict__ wp1,
                       _Float16* __restrict__ wp2, _Float16* __restrict__ wp3,
                       _Float16* __restrict__ wpB)
{
    int i = blockIdx.x * 256 + threadIdx.x;
    if (i < 262144) {                                   // hi16, x8
        int e = i * 8;
        half8 v;
#pragma unroll
        for (int k = 0; k < 8; ++k) v[k] = (_Float16)hi[e + k];
        *(half8*)(hi16 + e) = v;
        return;
    }
    i -= 262144;
    if (i < 36864) {        // wp1 [kt9][nt8][512]; kt0-7: K=256=[hs|hi]; kt8: r col
        int fragid = i >> 9, lj = i & 511;
        int kt = fragid >> 3, nt = fragid & 7;
        int l = lj >> 3, j = lj & 7;
        int klocal = (l >> 4) * 8 + j;
        int o = nt * 16 + (l & 15);
        float v;
        if (kt < 8)      v = W1[o * 257 + kt * 32 + klocal];
        else             v = (klocal == 0) ? W1[o * 257 + 256] : 0.0f;
        wp1[i] = (_Float16)v;
        return;
    }
    i -= 36864;
    if (i < 8192) {                        // wp2 [kt4][nt4][512]; K=128
        int fragid = i >> 9, lj = i & 511;
        int kt = fragid >> 2, nt = fragid & 3;
        int l = lj >> 3, j = lj & 7;
        int k = kt * 32 + (l >> 4) * 8 + j;
        int o = nt * 16 + (l & 15);
        wp2[i] = (_Float16)W2[o * 128 + k];
        return;
    }
    i -= 8192;
    if (i < 1024) {                        // wp3 [kt2][512]; K=64
        int kt = i >> 9, lj = i & 511;
        int l = lj >> 3, j = lj & 7;
        int k = kt * 32 + (l >> 4) * 8 + j;
        int c = l & 15;
        wp3[i] = (_Float16)((c < 8) ? W3[c * 64 + k] : 0.0f);
        return;
    }
    i -= 1024;
    if (i < 81920) {                       // wpB [kt5][ntile32][512]
        int frag = i >> 9, lj = i & 511;
        int kt = frag >> 5, ntile = frag & 31;
        int l = lj >> 3, j = lj & 7;
        int klocal = (l >> 4) * 8 + j;
        int col = ntile * 16 + (l & 15);
        float v;
        if (kt < 4) v = W_hh[col * 128 + kt * 32 + klocal];
        else        v = (klocal < 8) ? W_ih[col * 8 + klocal] : 0.0f;
        wpB[i] = (_Float16)v;
    }
}

// ---------------- wavefront megakernel: 256 blocks x 512 thr ----------------
__global__ __launch_bounds__(512, 2) void fused_k(
    const float* __restrict__ x, const _Float16* __restrict__ hi16,
    const float* __restrict__ r, const _Float16* __restrict__ wpB,
    const float* __restrict__ b_ih, const float* __restrict__ b_hh,
    const _Float16* __restrict__ wp1, const _Float16* __restrict__ wp2,
    const _Float16* __restrict__ wp3, const float* __restrict__ b1,
    const float* __restrict__ b2, const float* __restrict__ b3,
    const float* __restrict__ Wf, const float* __restrict__ bfp,
    float* __restrict__ out)
{
    __shared__ __align__(16) _Float16 zone[2][4][640];   // 10 KB: h, 16 rows x pad40
    __shared__ __align__(16) _Float16 curA[4][64][32];   // 16 KB: x per roll/t/seq
    __shared__ __align__(16) _Float16 h1L[16 * 136];     // 4.25 KB
    __shared__ __align__(16) _Float16 h2L[16 * 72];      // 2.25 KB

    const int t  = threadIdx.x;
    const int cg = t >> 6, l = t & 63;
    const int li = l & 15, lk = l >> 4;
    const int nblk = blockIdx.x, q0 = nblk * 4;

    // ---- LSTM weight frags (gate order f,i,g,o = src 1,0,2,3), AGPR-pinned
    const int gsrc[4] = {1, 0, 2, 3};
    half8 bw[4][5];
#pragma unroll
    for (int g = 0; g < 4; ++g)
#pragma unroll
        for (int kt = 0; kt < 5; ++kt) {
            bw[g][kt] = *(const half8*)(wpB + (size_t)(kt * 32 + gsrc[g] * 8 + cg) * 512 + l * 8);
            asm volatile("" : "+a"(bw[g][kt]));
        }
    f32x4 bs4[4];
#pragma unroll
    for (int g = 0; g < 4; ++g) {
        int gc = gsrc[g] * 128 + cg * 16 + li;
        float bv = b_ih[gc] + b_hh[gc];
        bs4[g] = (f32x4){bv, bv, bv, bv};
    }

    // zero zone (both bufs) and curA[1..3] (avoid NaN garbage on idle rows)
    for (int i = t; i < 2560; i += 512) ((uint*)zone)[i] = 0;
    for (int i = t; i < 3072; i += 512) ((uint*)&curA[1][0][0])[i] = 0;
    if (t < 256) {   // stage roll-0 x: x[:,63,q0..q0+3,:] -> curA[0]
        int st = t >> 2, tt = t & 3;
        const float* src = x + (size_t)st * 524288 + 63 * 8192 + (q0 + tt) * 8;
        half8 v;
#pragma unroll
        for (int k = 0; k < 8; ++k) v[k] = (_Float16)src[k];
        *(half8*)&curA[0][st][tt * 8] = v;
    }
    float cc[4] = {0.0f, 0.0f, 0.0f, 0.0f};
    __syncthreads();

    const f32x4 z4 = (f32x4){0.0f, 0.0f, 0.0f, 0.0f};
    const int zpl = cg >> 1, jl = (cg & 1) * 16 + li;
    const int roffL = li * 40 + lk * 8;     // 16 distinct rows (all real now)
    const int jx = li >> 2, sx = li & 3;    // A-row -> (roll, seq)
    const float b1v = b1[cg * 16 + li];
    const float b2v = (cg < 4) ? b2[cg * 16 + li] : 0.0f;
    const float b3v = (li < 8) ? b3[li] : 0.0f;
    const float wfv = (li < 8) ? Wf[li] : 0.0f;
    const float bfv = bfp[0];

#pragma unroll 1
    for (int T = 0; T < 67; ++T) {
        const int p = T & 1, pn = p ^ 1;
        const int tb = (T - jx) & 63;       // per-A-row roll timestep (clamped)

        // x A-frag (LDS; same addr for all lk -> broadcast) + global prefetch
        // of hi/r rows (stay in flight across the lgkm-only barrier)
        half8 xa = *(const half8*)&curA[jx][tb][sx * 8];
        half8 ahi[4];
#pragma unroll
        for (int kt = 0; kt < 4; ++kt)
            ahi[kt] = *(const half8*)(hi16 + ((size_t)(tb * 256 + nblk)) * 128
                                      + kt * 32 + lk * 8);
        half8 arf = (half8){0, 0, 0, 0, 0, 0, 0, 0};
        if (lk == 0) arf[0] = (_Float16)r[tb * 4 + jx];

        // ---- LSTM: 20 MFMA/wave, 16 real recurrences ----
        half8 ah[4];
#pragma unroll
        for (int kt = 0; kt < 4; ++kt)
            ah[kt] = *(const half8*)&zone[p][kt][roffL];

        f32x4 a0[4], a1[4];
#pragma unroll
        for (int g = 0; g < 4; ++g)
            a0[g] = MFMAH(xa, bw[g][4], bs4[g]);
#pragma unroll
        for (int g = 0; g < 4; ++g) {
            a0[g] = MFMAH(ah[0], bw[g][0], a0[g]);
            a1[g] = MFMAH(ah[2], bw[g][2], z4);
        }
#pragma unroll
        for (int g = 0; g < 4; ++g) {
            a0[g] = MFMAH(ah[1], bw[g][1], a0[g]);
            a1[g] = MFMAH(ah[3], bw[g][3], a1[g]);
        }

        // gates: 4 items/lane (roll lk, seq reg); inactive rolls masked to 0
        const int troll = T - lk;
        const bool act = (unsigned)troll < 64u;
        _Float16 hw[4];
#pragma unroll
        for (int reg = 0; reg < 4; ++reg) {
            float pf = a0[0][reg] + a1[0][reg];
            float pi = a0[1][reg] + a1[1][reg];
            float pg = a0[2][reg] + a1[2][reg];
            float po = a0[3][reg] + a1[3][reg];
            float ccp = (troll == 0) ? 0.0f : cc[reg];
            float ncc = sigf(pf) * ccp + sigf(pi) * tanh_f(pg);
            float hv  = sigf(po) * tanh_f(ncc);
            cc[reg] = act ? ncc : 0.0f;
            hw[reg] = act ? (_Float16)hv : (_Float16)0.0f;
        }
#pragma unroll
        for (int reg = 0; reg < 4; ++reg)
            zone[pn][zpl][(lk * 4 + reg) * 40 + jl] = hw[reg];
        asm volatile("s_waitcnt lgkmcnt(0)\n\ts_barrier" ::: "memory");

        // ---- G1: h1 = relu([h|hi|r] W1^T + b1); wave cg -> ntile cg; 4||5 ----
        f32x4 c0 = (f32x4){b1v, b1v, b1v, b1v}, c1 = z4;
#pragma unroll
        for (int kt = 0; kt < 4; ++kt) {
            half8 az = *(const half8*)&zone[pn][kt][roffL];
            half8 bv = *(const half8*)(wp1 + (size_t)(kt * 8 + cg) * 512 + l * 8);
            c0 = MFMAH(az, bv, c0);
            half8 bv2 = *(const half8*)(wp1 + (size_t)((kt + 4) * 8 + cg) * 512 + l * 8);
            c1 = MFMAH(ahi[kt], bv2, c1);
        }
        {
            half8 bv = *(const half8*)(wp1 + (size_t)(8 * 8 + cg) * 512 + l * 8);
            c1 = MFMAH(arf, bv, c1);
        }
#pragma unroll
        for (int reg = 0; reg < 4; ++reg) {
            float v = fmaxf(c0[reg] + c1[reg], 0.0f);
            h1L[(lk * 4 + reg) * 136 + cg * 16 + li] = (_Float16)v;
        }
        asm volatile("s_waitcnt lgkmcnt(0)\n\ts_barrier" ::: "memory");

        // ---- G2: h2 = relu(h1 W2^T + b2); waves 0-3 -> ntile cg; 2||2 ----
        if (cg < 4) {
            f32x4 d0 = (f32x4){b2v, b2v, b2v, b2v}, d1 = z4;
#pragma unroll
            for (int kt = 0; kt < 4; ++kt) {
                half8 av = *(const half8*)&h1L[li * 136 + kt * 32 + lk * 8];
                half8 bv = *(const half8*)(wp2 + (size_t)(kt * 4 + cg) * 512 + l * 8);
                if (kt & 1) d1 = MFMAH(av, bv, d1);
                else        d0 = MFMAH(av, bv, d0);
            }
#pragma unroll
            for (int reg = 0; reg < 4; ++reg) {
                float v = fmaxf(d0[reg] + d1[reg], 0.0f);
                h2L[(lk * 4 + reg) * 72 + cg * 16 + li] = (_Float16)v;
            }
        }
        asm volatile("s_waitcnt lgkmcnt(0)\n\ts_barrier" ::: "memory");

        // ---- G3 + epilogue: wave 0; pr -> curA[roll+1] (next roll's x), head -> out
        if (cg == 0) {
            f32x4 e = z4;
#pragma unroll
            for (int kt = 0; kt < 2; ++kt) {
                half8 av = *(const half8*)&h2L[li * 72 + kt * 32 + lk * 8];
                half8 bv = *(const half8*)(wp3 + (size_t)kt * 512 + l * 8);
                e = MFMAH(av, bv, e);
            }
            float fr[4];
#pragma unroll
            for (int reg = 0; reg < 4; ++reg) {   // item (roll lk, seq reg, b=troll)
                float pr = e[reg] + b3v;
                if (act && lk < 3 && li < 8)
                    curA[lk + 1][troll][reg * 8 + li] = (_Float16)pr;
                fr[reg] = (act && li < 8) ? fmaxf(pr, 0.0f) * wfv : 0.0f;
            }
#pragma unroll
            for (int reg = 0; reg < 4; ++reg) {
                fr[reg] += __shfl_xor(fr[reg], 1);
                fr[reg] += __shfl_xor(fr[reg], 2);
                fr[reg] += __shfl_xor(fr[reg], 4);
            }
            if (li == 0 && act) {
                float v = fr[0] + fr[1] + fr[2] + fr[3] + 4.0f * bfv;
                out[((size_t)troll * 256 + nblk) * 4 + lk] = v;
            }
        }
        asm volatile("s_waitcnt lgkmcnt(0)\n\ts_barrier" ::: "memory");
    }
}

extern "C" void kernel_launch(void* const* d_in, const int* in_sizes, int n_in,
                              void* d_out, int out_size, void* d_ws, size_t ws_size,
                              hipStream_t stream)
{
    const float* x   = (const float*)d_in[0];
    const float* hi  = (const float*)d_in[1];
    const float* r   = (const float*)d_in[2];
    const float* Wih = (const float*)d_in[3];
    const float* Whh = (const float*)d_in[4];
    const float* bih = (const float*)d_in[5];
    const float* bhh = (const float*)d_in[6];
    const float* W1  = (const float*)d_in[7];
    const float* b1  = (const float*)d_in[8];
    const float* W2  = (const float*)d_in[9];
    const float* b2  = (const float*)d_in[10];
    const float* W3  = (const float*)d_in[11];
    const float* b3  = (const float*)d_in[12];
    const float* Wf  = (const float*)d_in[13];
    const float* bf  = (const float*)d_in[14];
    float* out = (float*)d_out;

    _Float16* hi16 = (_Float16*)d_ws;                  // 2097152
    _Float16* wp1  = hi16 + 2097152;                   // 36864 (9 kts)
    _Float16* wp2  = wp1 + 36864;                      // 8192
    _Float16* wp3  = wp2 + 8192;                       // 1024
    _Float16* wpB  = wp3 + 1024;                       // 81920

    prep_k<<<1524, 256, 0, stream>>>(hi, W1, W2, W3, Whh, Wih,
                                     hi16, wp1, wp2, wp3, wpB);
    fused_k<<<256, 512, 0, stream>>>(x, hi16, r, wpB, bih, bhh,
                                     wp1, wp2, wp3, b1, b2, b3, Wf, bf, out);
}